// Round 10
// baseline (292.492 us; speedup 1.0000x reference)
//
#include <hip/hip_runtime.h>
#include <hip/hip_bf16.h>

#define NN 50000
#define EE 800000
#define HH 128
#define BB 256
#define CLS 10
#define MLPH 64
#define CAP 64            // per-node capacity (max degree; Poisson(16) tail << 64; verified R5-R9)

#define NBUK 782          // ceil(NN/64) buckets (dst>>6), 64 nodes each
#define NBLK 250          // binning blocks
#define EPB 3200          // edges per binning block: 250*3200 = 800000 exactly
#define SCAN_N (NBUK * NBLK)       // 195500
#define SCAN_BLKS 764     // ceil(SCAN_N/256)

typedef __attribute__((ext_vector_type(8))) short short8;
typedef __attribute__((ext_vector_type(4))) float floatx4;

__device__ __forceinline__ float bflo(unsigned u){ unsigned v = u << 16; return __builtin_bit_cast(float, v); }
__device__ __forceinline__ float bfhi(unsigned u){ unsigned v = u & 0xffff0000u; return __builtin_bit_cast(float, v); }
__device__ __forceinline__ unsigned short f2bf(float f){
  unsigned u = __builtin_bit_cast(unsigned, f);
  u += 0x7fffu + ((u >> 16) & 1u);
  return (unsigned short)(u >> 16);
}
__device__ __forceinline__ unsigned pack2(float a, float b){
  return (unsigned)f2bf(a) | ((unsigned)f2bf(b) << 16);
}

// ---------------- binning pass 1: per-block histogram by dst>>6 (LDS atomics only) ----------------
__global__ __launch_bounds__(256) void bin_count_k(const int* __restrict__ dst, int* __restrict__ cnts){
  __shared__ int hist[NBUK];
  int t = threadIdx.x, blk = blockIdx.x;
  for (int i = t; i < NBUK; i += 256) hist[i] = 0;
  __syncthreads();
  int e0 = blk * EPB;
  #pragma unroll 4
  for (int i = 0; i < 12; ++i) atomicAdd(&hist[dst[e0 + i * 256 + t] >> 6], 1);
  if (t < 128) atomicAdd(&hist[dst[e0 + 3072 + t] >> 6], 1);
  __syncthreads();
  for (int u = t; u < NBUK; u += 256) cnts[u * NBLK + blk] = hist[u];   // bucket-major
}

// ---------------- hierarchical exclusive scan over cnts[SCAN_N] ----------------
__global__ __launch_bounds__(256) void scanA_k(int* data, int* bsum){
  __shared__ int sd[256];
  int t = threadIdx.x;
  int i = blockIdx.x * 256 + t;
  int v = (i < SCAN_N) ? data[i] : 0;
  sd[t] = v; __syncthreads();
  for (int off = 1; off < 256; off <<= 1){
    int add = (t >= off) ? sd[t - off] : 0;
    __syncthreads();
    sd[t] += add;
    __syncthreads();
  }
  if (i < SCAN_N) data[i] = sd[t] - v;          // exclusive within scan-block
  if (t == 255) bsum[blockIdx.x] = sd[255];
}
__global__ __launch_bounds__(256) void scanB_k(int* bsum){
  __shared__ int sd[256];
  __shared__ int carry;
  int t = threadIdx.x;
  if (t == 0) carry = 0;
  __syncthreads();
  for (int c = 0; c < 3; ++c){                   // 3*256 = 768 >= SCAN_BLKS
    int i = c * 256 + t;
    int v = (i < SCAN_BLKS) ? bsum[i] : 0;
    sd[t] = v; __syncthreads();
    for (int off = 1; off < 256; off <<= 1){
      int add = (t >= off) ? sd[t - off] : 0;
      __syncthreads();
      sd[t] += add;
      __syncthreads();
    }
    if (i < SCAN_BLKS) bsum[i] = carry + sd[t] - v;
    __syncthreads();
    if (t == 255) carry += sd[255];
    __syncthreads();
  }
}

// ---------------- binning pass 2: rank-based scatter, zero global atomics ----------------
// record: x = src | ((dst&63)<<16), y = bits(ew)
__global__ __launch_bounds__(256) void bin_scatter_k(const int* __restrict__ src, const int* __restrict__ dst,
                                                     const float* __restrict__ ew,
                                                     const int* __restrict__ sc, const int* __restrict__ bsum,
                                                     int2* __restrict__ ebin){
  __shared__ int lbase[NBUK];
  __shared__ int lrank[NBUK];
  int t = threadIdx.x, blk = blockIdx.x;
  for (int i = t; i < NBUK; i += 256){
    int idx = i * NBLK + blk;
    lbase[i] = sc[idx] + bsum[idx >> 8];
    lrank[i] = 0;
  }
  __syncthreads();
  int e0 = blk * EPB;
  for (int i = 0; i < 13; ++i){
    int off = i * 256 + t;
    if (off < EPB){
      int e = e0 + off;
      int d = dst[e];
      int u = d >> 6;
      int r = atomicAdd(&lrank[u], 1);
      int2 rec; rec.x = src[e] | ((d & 63) << 16); rec.y = __builtin_bit_cast(int, ew[e]);
      ebin[lbase[u] + r] = rec;
    }
  }
}

// ---------------- binning pass 3: within-bucket sort into per-node CAP slots + cnt + dinv ----------------
// ebuf record: 4B = src | (bf16(ew) << 16)
__global__ __launch_bounds__(256) void bucket_sort_k(const int2* __restrict__ ebin, const int* __restrict__ sc,
                                                     const int* __restrict__ bsum,
                                                     unsigned* __restrict__ ebuf, int* __restrict__ cnt,
                                                     float* __restrict__ dinv){
  __shared__ int hist[64];
  __shared__ float wsum[64];
  int t = threadIdx.x, u = blockIdx.x;
  if (t < 64){ hist[t] = 0; wsum[t] = 0.0f; }
  __syncthreads();
  int i0 = u * NBLK;
  int s0 = sc[i0] + bsum[i0 >> 8];
  int s1 = EE;
  if (u + 1 < NBUK){ int i1 = (u + 1) * NBLK; s1 = sc[i1] + bsum[i1 >> 8]; }
  for (int e = s0 + t; e < s1; e += 256){
    int2 rec = ebin[e];
    int dl = rec.x >> 16;
    float w = __builtin_bit_cast(float, rec.y);
    int r = atomicAdd(&hist[dl], 1);
    atomicAdd(&wsum[dl], w);
    if (r < CAP){
      unsigned c4 = (unsigned)(rec.x & 0xFFFF) | ((unsigned)f2bf(w) << 16);
      ebuf[((size_t)(u * 64 + dl)) * CAP + r] = c4;
    }
  }
  __syncthreads();
  if (t < 64){
    int n = u * 64 + t;
    if (n < NN){
      cnt[n] = min(hist[t], CAP);
      dinv[n] = rsqrtf(1.0f + wsum[t]);          // self-loop weight 1
    }
  }
}

// ---------------- fused prep: blocks 0..191 transpose W1/W2/W3; block 192 gbounds + BN zero ----------------
__global__ __launch_bounds__(256) void prep_k(const float* W1, const float* W2, const float* W3,
                                              unsigned short* Wt1, unsigned short* Wt2, unsigned short* Wt3,
                                              const int* __restrict__ batch, int* gstart,
                                              float* bnsum, float* bnsqs){
  int blk = blockIdx.x, t = threadIdx.x;
  if (blk == 192){
    int b = t;
    if (b < HH){ bnsum[b] = 0.0f; bnsqs[b] = 0.0f; }
    int lo = 0, hi = NN;
    while (lo < hi){
      int mid = (lo + hi) >> 1;
      if (batch[mid] < b) lo = mid + 1; else hi = mid;
    }
    gstart[b] = lo;
    if (b == 0) gstart[BB] = NN;
    return;
  }
  int gi = blk * 256 + t;
  int w = gi >> 14;
  int i = gi & 16383;
  const float* W = (w == 0) ? W1 : (w == 1) ? W2 : W3;
  unsigned short* Wt = (w == 0) ? Wt1 : (w == 1) ? Wt2 : Wt3;
  int n = i >> 7, k = i & 127;
  Wt[i] = f2bf(W[(k << 7) + n]);
}

// ---------------- GEMM (bf16 input): G = dinv[m] * (X[M,128] @ W[128,128]) ----------------
// Operand-swapped MFMA (verified R6-R9). 16 rows/wave, 64 rows/block -> 782 blocks (12 waves/CU).
__global__ __launch_bounds__(256) void gemm64_k(const unsigned short* __restrict__ X,
                                                const unsigned short* __restrict__ Wt,
                                                const float* __restrict__ dinv,
                                                unsigned short* __restrict__ Gout, int nrows){
  __shared__ __align__(16) unsigned short lw[HH * 136];
  {
    const float4* s4 = (const float4*)Wt;
    float4* d4 = (float4*)lw;
    for (int i = threadIdx.x; i < 2048; i += 256){
      int row = i >> 4, off = i & 15;
      d4[row * 17 + off] = s4[i];
    }
  }
  __syncthreads();
  int wave = threadIdx.x >> 6;
  int lane = threadIdx.x & 63;
  int r16 = lane & 15, quad = lane >> 4;
  int m = blockIdx.x * 64 + wave * 16 + r16;

  short8 xfrag[4];
  int msafe = (m < nrows) ? m : 0;
  const short8* xrow = (const short8*)(X + (size_t)msafe * HH);
  #pragma unroll
  for (int kk = 0; kk < 4; ++kk) xfrag[kk] = xrow[4 * kk + quad];
  float dv = (m < nrows) ? dinv[m] : 0.0f;

  #pragma unroll
  for (int ct = 0; ct < 8; ++ct){
    floatx4 acc = {0.f,0.f,0.f,0.f};
    const short8* wrow = (const short8*)(lw + (16 * ct + r16) * 136);
    #pragma unroll
    for (int kk = 0; kk < 4; ++kk)
      acc = __builtin_amdgcn_mfma_f32_16x16x32_bf16(wrow[4 * kk + quad], xfrag[kk], acc, 0, 0, 0);
    int ch0 = ct * 16 + quad * 4;            // D: col=lane&15 (node), row=quad*4+r (channel)
    if (m < nrows){
      uint2 pk; pk.x = pack2(acc[0] * dv, acc[1] * dv);
      pk.y = pack2(acc[2] * dv, acc[3] * dv);
      ((uint2*)Gout)[((size_t)m * HH + ch0) >> 2] = pk;
    }
  }
}

// ---------------- GEMM (f32 input, layer 1) ----------------
__global__ __launch_bounds__(256) void gemm64_f32_k(const float* __restrict__ X,
                                                    const unsigned short* __restrict__ Wt,
                                                    const float* __restrict__ dinv,
                                                    unsigned short* __restrict__ Gout, int nrows){
  __shared__ __align__(16) unsigned short lw[HH * 136];
  {
    const float4* s4 = (const float4*)Wt;
    float4* d4 = (float4*)lw;
    for (int i = threadIdx.x; i < 2048; i += 256){
      int row = i >> 4, off = i & 15;
      d4[row * 17 + off] = s4[i];
    }
  }
  __syncthreads();
  int wave = threadIdx.x >> 6;
  int lane = threadIdx.x & 63;
  int r16 = lane & 15, quad = lane >> 4;
  int m = blockIdx.x * 64 + wave * 16 + r16;

  short8 xfrag[4];
  int msafe = (m < nrows) ? m : 0;
  const float4* xr = (const float4*)(X + (size_t)msafe * HH);
  #pragma unroll
  for (int kk = 0; kk < 4; ++kk){
    float4 aA = xr[kk * 8 + quad * 2];
    float4 aB = xr[kk * 8 + quad * 2 + 1];
    uint4 pk;
    pk.x = pack2(aA.x, aA.y); pk.y = pack2(aA.z, aA.w);
    pk.z = pack2(aB.x, aB.y); pk.w = pack2(aB.z, aB.w);
    xfrag[kk] = __builtin_bit_cast(short8, pk);
  }
  float dv = (m < nrows) ? dinv[m] : 0.0f;

  #pragma unroll
  for (int ct = 0; ct < 8; ++ct){
    floatx4 acc = {0.f,0.f,0.f,0.f};
    const short8* wrow = (const short8*)(lw + (16 * ct + r16) * 136);
    #pragma unroll
    for (int kk = 0; kk < 4; ++kk)
      acc = __builtin_amdgcn_mfma_f32_16x16x32_bf16(wrow[4 * kk + quad], xfrag[kk], acc, 0, 0, 0);
    int ch0 = ct * 16 + quad * 4;
    if (m < nrows){
      uint2 pk; pk.x = pack2(acc[0] * dv, acc[1] * dv);
      pk.y = pack2(acc[2] * dv, acc[3] * dv);
      ((uint2*)Gout)[((size_t)m * HH + ch0) >> 2] = pk;
    }
  }
}

// ---------------- aggregation: wave-per-node, 4 edges/step via 16-lane x 16B gathers ----------------
__global__ __launch_bounds__(256) void aggregate_k(const unsigned short* __restrict__ Gin,
                                                   const unsigned* __restrict__ ebuf,
                                                   const int* __restrict__ cnt,
                                                   const float* __restrict__ dinv,
                                                   const float* __restrict__ bias,
                                                   unsigned short* __restrict__ Xout){
  __shared__ float part[4][4][16][8];          // [wave][group][lane16][8ch] = 8 KB
  int wv = threadIdx.x >> 6, lane = threadIdx.x & 63;
  int node = blockIdx.x * 4 + wv;              // NN = 4*12500 exactly
  int g = lane >> 4, l = lane & 15;
  int c = min(cnt[node], CAP);
  unsigned rec = 0;                            // src=0, w=+0.0 bf16
  if (lane < c) rec = ebuf[(size_t)node * CAP + lane];
  float acc[8] = {0,0,0,0,0,0,0,0};
  const uint4* G4 = (const uint4*)Gin;
  int steps = (c + 3) >> 2;
  #pragma unroll 4
  for (int j = 0; j < steps; ++j){
    int idx = 4 * j + g;
    unsigned r = (unsigned)__shfl((int)rec, idx);
    int sx = r & 0xFFFF;
    float w = bfhi(r);
    if (idx >= c){ sx = 0; w = 0.0f; }
    uint4 q = G4[(size_t)sx * 16 + l];
    acc[0] = fmaf(w, bflo(q.x), acc[0]);
    acc[1] = fmaf(w, bfhi(q.x), acc[1]);
    acc[2] = fmaf(w, bflo(q.y), acc[2]);
    acc[3] = fmaf(w, bfhi(q.y), acc[3]);
    acc[4] = fmaf(w, bflo(q.z), acc[4]);
    acc[5] = fmaf(w, bfhi(q.z), acc[5]);
    acc[6] = fmaf(w, bflo(q.w), acc[6]);
    acc[7] = fmaf(w, bfhi(q.w), acc[7]);
  }
  #pragma unroll
  for (int k = 0; k < 8; ++k) part[wv][g][l][k] = acc[k];
  __syncthreads();
  int l0 = lane >> 2, k0 = (lane & 3) * 2;
  float a0 = part[wv][0][l0][k0]   + part[wv][1][l0][k0]   + part[wv][2][l0][k0]   + part[wv][3][l0][k0];
  float a1 = part[wv][0][l0][k0+1] + part[wv][1][l0][k0+1] + part[wv][2][l0][k0+1] + part[wv][3][l0][k0+1];
  unsigned gs = ((const unsigned*)Gin)[(size_t)node * 64 + lane];
  a0 += bflo(gs); a1 += bfhi(gs);
  float di = dinv[node];
  float2 bb = ((const float2*)bias)[lane];
  a0 = fmaxf(fmaf(di, a0, bb.x), 0.0f);
  a1 = fmaxf(fmaf(di, a1, bb.y), 0.0f);
  ((unsigned*)Xout)[(size_t)node * 64 + lane] = pack2(a0, a1);
}

// ---------------- pooling + BN stats: one block per graph (batch sorted) ----------------
__global__ __launch_bounds__(256) void pool_k(const unsigned short* __restrict__ H3,
                                              const int* __restrict__ gstart,
                                              float* __restrict__ S, float* bnsum, float* bnsqs,
                                              float* cntf){
  __shared__ float rs0[256], rs1[256], rq0[256], rq1[256];
  int b = blockIdx.x;
  int t = threadIdx.x, colc = t & 63, sub = t >> 6;
  int start = gstart[b], end = gstart[b + 1];
  const unsigned* Hrow = (const unsigned*)H3;
  float s0 = 0, s1 = 0, q0 = 0, q1 = 0;
  #pragma unroll 4
  for (int n = start + sub; n < end; n += 4){
    unsigned h = Hrow[(size_t)n * 64 + colc];
    float a = bflo(h), c = bfhi(h);
    s0 += a; s1 += c; q0 += a * a; q1 += c * c;
  }
  rs0[t] = s0; rs1[t] = s1; rq0[t] = q0; rq1[t] = q1;
  __syncthreads();
  if (sub == 0){
    float t0 = rs0[colc] + rs0[colc + 64] + rs0[colc + 128] + rs0[colc + 192];
    float t1 = rs1[colc] + rs1[colc + 64] + rs1[colc + 128] + rs1[colc + 192];
    float u0 = rq0[colc] + rq0[colc + 64] + rq0[colc + 128] + rq0[colc + 192];
    float u1 = rq1[colc] + rq1[colc + 64] + rq1[colc + 128] + rq1[colc + 192];
    S[b * HH + 2 * colc]     = t0;
    S[b * HH + 2 * colc + 1] = t1;
    atomicAdd(&bnsum[2 * colc], t0);
    atomicAdd(&bnsum[2 * colc + 1], t1);
    atomicAdd(&bnsqs[2 * colc], u0);
    atomicAdd(&bnsqs[2 * colc + 1], u1);
    if (t == 0) cntf[b] = (float)(end - start);
  }
}

// ---------------- BN affine on pooled means + MLP head (f32 out) ----------------
__global__ __launch_bounds__(64) void mlp_head_k(const float* __restrict__ S, const float* __restrict__ cntf,
                                                 const float* __restrict__ bnsum, const float* __restrict__ bnsqs,
                                                 const float* gamma, const float* beta,
                                                 const float* Wm1, const float* bm1,
                                                 const float* Wm2, const float* bm2,
                                                 float* out){
  __shared__ float gb[HH];
  __shared__ float t[MLPH];
  int b = blockIdx.x, j = threadIdx.x;
  float inv = 1.0f / fmaxf(cntf[b], 1.0f);
  for (int c = j; c < HH; c += 64){
    float mu = bnsum[c] * (1.0f / NN);
    float var = bnsqs[c] * (1.0f / NN) - mu * mu;
    float istd = rsqrtf(var + 1e-5f);
    float g = S[b * HH + c] * inv;
    gb[c] = (g - mu) * istd * gamma[c] + beta[c];
  }
  __syncthreads();
  float acc = bm1[j];
  for (int k = 0; k < HH; ++k) acc = fmaf(gb[k], Wm1[k * MLPH + j], acc);
  t[j] = acc;
  __syncthreads();
  if (j < CLS){
    float o = bm2[j];
    for (int k = 0; k < MLPH; ++k) o = fmaf(t[k], Wm2[k * CLS + j], o);
    out[b * CLS + j] = o;
  }
}

static inline size_t al(size_t x){ return (x + 255) & ~(size_t)255; }

extern "C" void kernel_launch(void* const* d_in, const int* in_sizes, int n_in,
                              void* d_out, int out_size, void* d_ws, size_t ws_size,
                              hipStream_t stream){
  const float* x     = (const float*)d_in[0];
  const int*   ei    = (const int*)d_in[1];          // [2][E]: src, dst
  const float* ea    = (const float*)d_in[2];
  const int*   batch = (const int*)d_in[3];
  const float* W1 = (const float*)d_in[4];
  const float* b1 = (const float*)d_in[5];
  const float* W2 = (const float*)d_in[6];
  const float* b2 = (const float*)d_in[7];
  const float* W3 = (const float*)d_in[8];
  const float* b3 = (const float*)d_in[9];
  const float* gamma = (const float*)d_in[10];
  const float* beta  = (const float*)d_in[11];
  const float* Wm1 = (const float*)d_in[12];
  const float* bm1 = (const float*)d_in[13];
  const float* Wm2 = (const float*)d_in[14];
  const float* bm2 = (const float*)d_in[15];
  const int* srcv = ei;
  const int* dstv = ei + EE;

  char* p = (char*)d_ws;
  float* dinv   = (float*)p;            p += al(NN * 4);
  int*   cnt    = (int*)p;              p += al(NN * 4);
  int*   cnts   = (int*)p;              p += al((size_t)SCAN_N * 4);
  int*   bsum   = (int*)p;              p += al(SCAN_BLKS * 4);
  int*   gstart = (int*)p;              p += al((BB + 1) * 4);
  int2*  ebin   = (int2*)p;             p += al((size_t)EE * 8);
  unsigned* ebuf = (unsigned*)p;        p += al((size_t)NN * CAP * 4);
  unsigned short* Wt1  = (unsigned short*)p; p += al(HH * HH * 2);
  unsigned short* Wt2  = (unsigned short*)p; p += al(HH * HH * 2);
  unsigned short* Wt3  = (unsigned short*)p; p += al(HH * HH * 2);
  unsigned short* bufA = (unsigned short*)p; p += al((size_t)NN * HH * 2);
  unsigned short* bufB = (unsigned short*)p; p += al((size_t)NN * HH * 2);
  float* S     = (float*)p;             p += al(BB * HH * 4);
  float* bnsum = (float*)p;             p += al(HH * 4);
  float* bnsqs = (float*)p;             p += al(HH * 4);
  float* cntf  = (float*)p;             p += al(BB * 4);

  const int nT = 256;
  dim3 gW((NN + 3) / 4);

  bin_count_k<<<dim3(NBLK), nT, 0, stream>>>(dstv, cnts);
  scanA_k<<<dim3(SCAN_BLKS), nT, 0, stream>>>(cnts, bsum);
  scanB_k<<<dim3(1), nT, 0, stream>>>(bsum);
  bin_scatter_k<<<dim3(NBLK), nT, 0, stream>>>(srcv, dstv, ea, cnts, bsum, ebin);
  bucket_sort_k<<<dim3(NBUK), nT, 0, stream>>>(ebin, cnts, bsum, ebuf, cnt, dinv);
  prep_k<<<dim3(193), nT, 0, stream>>>(W1, W2, W3, Wt1, Wt2, Wt3, batch, gstart, bnsum, bnsqs);

  dim3 gGemm((NN + 63) / 64);
  // layer 1 (f32 x read directly):  x -> bufA(G1) -> bufB(X2)
  gemm64_f32_k<<<gGemm, nT, 0, stream>>>(x, Wt1, dinv, bufA, NN);
  aggregate_k<<<gW, nT, 0, stream>>>(bufA, ebuf, cnt, dinv, b1, bufB);
  // layer 2
  gemm64_k<<<gGemm, nT, 0, stream>>>(bufB, Wt2, dinv, bufA, NN);
  aggregate_k<<<gW, nT, 0, stream>>>(bufA, ebuf, cnt, dinv, b2, bufB);
  // layer 3
  gemm64_k<<<gGemm, nT, 0, stream>>>(bufB, Wt3, dinv, bufA, NN);
  aggregate_k<<<gW, nT, 0, stream>>>(bufA, ebuf, cnt, dinv, b3, bufB);

  pool_k<<<dim3(BB), nT, 0, stream>>>(bufB, gstart, S, bnsum, bnsqs, cntf);
  mlp_head_k<<<dim3(BB), dim3(64), 0, stream>>>(S, cntf, bnsum, bnsqs, gamma, beta,
                                                Wm1, bm1, Wm2, bm2, (float*)d_out);
}

// Round 12
// 287.294 us; speedup vs baseline: 1.0181x; 1.0181x over previous
//
#include <hip/hip_runtime.h>
#include <hip/hip_bf16.h>

#define NN 50000
#define EE 800000
#define HH 128
#define BB 256
#define CLS 10
#define MLPH 64
#define CAP 64            // per-node capacity (max degree; Poisson(16) tail << 64; verified R5-R10)

#define NBUK 196          // ceil(NN/256) coarse buckets (dst>>8), 256 nodes each
#define NBLK 250          // binning blocks
#define EPB 3200          // edges per binning block: 250*3200 = 800000 exactly
#define SCAN_N (NBUK * NBLK)       // 49000
#define SCAN_BLKS 192     // ceil(SCAN_N/256)

typedef __attribute__((ext_vector_type(8))) short short8;
typedef __attribute__((ext_vector_type(4))) float floatx4;

__device__ __forceinline__ float bflo(unsigned u){ unsigned v = u << 16; return __builtin_bit_cast(float, v); }
__device__ __forceinline__ float bfhi(unsigned u){ unsigned v = u & 0xffff0000u; return __builtin_bit_cast(float, v); }
__device__ __forceinline__ unsigned short f2bf(float f){
  unsigned u = __builtin_bit_cast(unsigned, f);
  u += 0x7fffu + ((u >> 16) & 1u);
  return (unsigned short)(u >> 16);
}
__device__ __forceinline__ unsigned pack2(float a, float b){
  return (unsigned)f2bf(a) | ((unsigned)f2bf(b) << 16);
}

// ---------------- binning pass 1: per-block histogram by dst>>8 (LDS atomics only) ----------------
__global__ __launch_bounds__(256) void bin_count_k(const int* __restrict__ dst, int* __restrict__ cnts){
  __shared__ int hist[NBUK];
  int t = threadIdx.x, blk = blockIdx.x;
  if (t < NBUK) hist[t] = 0;
  __syncthreads();
  int e0 = blk * EPB;
  #pragma unroll 4
  for (int i = 0; i < 12; ++i) atomicAdd(&hist[dst[e0 + i * 256 + t] >> 8], 1);
  if (t < 128) atomicAdd(&hist[dst[e0 + 3072 + t] >> 8], 1);
  __syncthreads();
  if (t < NBUK) cnts[t * NBLK + blk] = hist[t];   // bucket-major
}

// ---------------- hierarchical exclusive scan over cnts[SCAN_N] ----------------
__global__ __launch_bounds__(256) void scanA_k(int* data, int* bsum){
  __shared__ int sd[256];
  int t = threadIdx.x;
  int i = blockIdx.x * 256 + t;
  int v = (i < SCAN_N) ? data[i] : 0;
  sd[t] = v; __syncthreads();
  for (int off = 1; off < 256; off <<= 1){
    int add = (t >= off) ? sd[t - off] : 0;
    __syncthreads();
    sd[t] += add;
    __syncthreads();
  }
  if (i < SCAN_N) data[i] = sd[t] - v;          // exclusive within scan-block
  if (t == 255) bsum[blockIdx.x] = sd[255];
}
__global__ __launch_bounds__(256) void scanB_k(int* bsum){
  __shared__ int sd[256];
  int t = threadIdx.x;
  int v = (t < SCAN_BLKS) ? bsum[t] : 0;
  sd[t] = v; __syncthreads();
  for (int off = 1; off < 256; off <<= 1){
    int add = (t >= off) ? sd[t - off] : 0;
    __syncthreads();
    sd[t] += add;
    __syncthreads();
  }
  if (t < SCAN_BLKS) bsum[t] = sd[t] - v;       // exclusive block offsets
}

// ---------------- binning pass 2: rank-based scatter, zero global atomics ----------------
// record: x = src | ((dst&255)<<16), y = bits(ew)
__global__ __launch_bounds__(256) void bin_scatter_k(const int* __restrict__ src, const int* __restrict__ dst,
                                                     const float* __restrict__ ew,
                                                     const int* __restrict__ sc, const int* __restrict__ bsum,
                                                     int2* __restrict__ ebin){
  __shared__ int lbase[NBUK];
  __shared__ int lrank[NBUK];
  int t = threadIdx.x, blk = blockIdx.x;
  if (t < NBUK){
    int idx = t * NBLK + blk;
    lbase[t] = sc[idx] + bsum[idx >> 8];
    lrank[t] = 0;
  }
  __syncthreads();
  int e0 = blk * EPB;
  for (int i = 0; i < 13; ++i){
    int off = i * 256 + t;
    if (off < EPB){
      int e = e0 + off;
      int d = dst[e];
      int u = d >> 8;
      int r = atomicAdd(&lrank[u], 1);
      int2 rec; rec.x = src[e] | ((d & 255) << 16); rec.y = __builtin_bit_cast(int, ew[e]);
      ebin[lbase[u] + r] = rec;
    }
  }
}

// ---------------- binning pass 3: within-bucket sort into per-node CAP slots + cnt + dinv ----------------
// ebuf record: 4B = src | (bf16(ew) << 16)
__global__ __launch_bounds__(256) void bucket_sort_k(const int2* __restrict__ ebin, const int* __restrict__ sc,
                                                     const int* __restrict__ bsum,
                                                     unsigned* __restrict__ ebuf, int* __restrict__ cnt,
                                                     float* __restrict__ dinv){
  __shared__ int hist[256];
  __shared__ float wsum[256];
  int t = threadIdx.x, u = blockIdx.x;
  hist[t] = 0; wsum[t] = 0.0f;
  __syncthreads();
  int i0 = u * NBLK;
  int s0 = sc[i0] + bsum[i0 >> 8];
  int s1 = EE;
  if (u + 1 < NBUK){ int i1 = (u + 1) * NBLK; s1 = sc[i1] + bsum[i1 >> 8]; }
  for (int e = s0 + t; e < s1; e += 256){
    int2 rec = ebin[e];
    int dl = rec.x >> 16;
    float w = __builtin_bit_cast(float, rec.y);
    int r = atomicAdd(&hist[dl], 1);
    atomicAdd(&wsum[dl], w);
    if (r < CAP){
      unsigned c4 = (unsigned)(rec.x & 0xFFFF) | ((unsigned)f2bf(w) << 16);
      ebuf[((size_t)(u * 256 + dl)) * CAP + r] = c4;
    }
  }
  __syncthreads();
  int n = u * 256 + t;
  if (n < NN){
    cnt[n] = min(hist[t], CAP);
    dinv[n] = rsqrtf(1.0f + wsum[t]);          // self-loop weight 1
  }
}

// ---------------- fused prep: blocks 0..191 transpose W1/W2/W3; block 192 gbounds + BN zero ----------------
__global__ __launch_bounds__(256) void prep_k(const float* W1, const float* W2, const float* W3,
                                              unsigned short* Wt1, unsigned short* Wt2, unsigned short* Wt3,
                                              const int* __restrict__ batch, int* gstart,
                                              float* bnsum, float* bnsqs){
  int blk = blockIdx.x, t = threadIdx.x;
  if (blk == 192){
    int b = t;
    if (b < HH){ bnsum[b] = 0.0f; bnsqs[b] = 0.0f; }
    int lo = 0, hi = NN;
    while (lo < hi){
      int mid = (lo + hi) >> 1;
      if (batch[mid] < b) lo = mid + 1; else hi = mid;
    }
    gstart[b] = lo;
    if (b == 0) gstart[BB] = NN;
    return;
  }
  int gi = blk * 256 + t;
  int w = gi >> 14;
  int i = gi & 16383;
  const float* W = (w == 0) ? W1 : (w == 1) ? W2 : W3;
  unsigned short* Wt = (w == 0) ? Wt1 : (w == 1) ? Wt2 : Wt3;
  int n = i >> 7, k = i & 127;
  Wt[i] = f2bf(W[(k << 7) + n]);
}

// ---------------- GEMM (bf16 input): G = dinv[m] * (X[M,128] @ W[128,128]) ----------------
// Operand-swapped MFMA (verified R6-R10). 16 rows/wave, 64 rows/block -> 782 blocks (12 waves/CU).
__global__ __launch_bounds__(256) void gemm64_k(const unsigned short* __restrict__ X,
                                                const unsigned short* __restrict__ Wt,
                                                const float* __restrict__ dinv,
                                                unsigned short* __restrict__ Gout, int nrows){
  __shared__ __align__(16) unsigned short lw[HH * 136];
  {
    const float4* s4 = (const float4*)Wt;
    float4* d4 = (float4*)lw;
    for (int i = threadIdx.x; i < 2048; i += 256){
      int row = i >> 4, off = i & 15;
      d4[row * 17 + off] = s4[i];
    }
  }
  __syncthreads();
  int wave = threadIdx.x >> 6;
  int lane = threadIdx.x & 63;
  int r16 = lane & 15, quad = lane >> 4;
  int m = blockIdx.x * 64 + wave * 16 + r16;

  short8 xfrag[4];
  int msafe = (m < nrows) ? m : 0;
  const short8* xrow = (const short8*)(X + (size_t)msafe * HH);
  #pragma unroll
  for (int kk = 0; kk < 4; ++kk) xfrag[kk] = xrow[4 * kk + quad];
  float dv = (m < nrows) ? dinv[m] : 0.0f;

  #pragma unroll
  for (int ct = 0; ct < 8; ++ct){
    floatx4 acc = {0.f,0.f,0.f,0.f};
    const short8* wrow = (const short8*)(lw + (16 * ct + r16) * 136);
    #pragma unroll
    for (int kk = 0; kk < 4; ++kk)
      acc = __builtin_amdgcn_mfma_f32_16x16x32_bf16(wrow[4 * kk + quad], xfrag[kk], acc, 0, 0, 0);
    int ch0 = ct * 16 + quad * 4;            // D: col=lane&15 (node), row=quad*4+r (channel)
    if (m < nrows){
      uint2 pk; pk.x = pack2(acc[0] * dv, acc[1] * dv);
      pk.y = pack2(acc[2] * dv, acc[3] * dv);
      ((uint2*)Gout)[((size_t)m * HH + ch0) >> 2] = pk;
    }
  }
}

// ---------------- GEMM (f32 input, layer 1): converts x in-register ----------------
__global__ __launch_bounds__(256) void gemm64_f32_k(const float* __restrict__ X,
                                                    const unsigned short* __restrict__ Wt,
                                                    const float* __restrict__ dinv,
                                                    unsigned short* __restrict__ Gout, int nrows){
  __shared__ __align__(16) unsigned short lw[HH * 136];
  {
    const float4* s4 = (const float4*)Wt;
    float4* d4 = (float4*)lw;
    for (int i = threadIdx.x; i < 2048; i += 256){
      int row = i >> 4, off = i & 15;
      d4[row * 17 + off] = s4[i];
    }
  }
  __syncthreads();
  int wave = threadIdx.x >> 6;
  int lane = threadIdx.x & 63;
  int r16 = lane & 15, quad = lane >> 4;
  int m = blockIdx.x * 64 + wave * 16 + r16;

  short8 xfrag[4];
  int msafe = (m < nrows) ? m : 0;
  const float4* xr = (const float4*)(X + (size_t)msafe * HH);
  #pragma unroll
  for (int kk = 0; kk < 4; ++kk){
    float4 aA = xr[kk * 8 + quad * 2];
    float4 aB = xr[kk * 8 + quad * 2 + 1];
    uint4 pk;
    pk.x = pack2(aA.x, aA.y); pk.y = pack2(aA.z, aA.w);
    pk.z = pack2(aB.x, aB.y); pk.w = pack2(aB.z, aB.w);
    xfrag[kk] = __builtin_bit_cast(short8, pk);
  }
  float dv = (m < nrows) ? dinv[m] : 0.0f;

  #pragma unroll
  for (int ct = 0; ct < 8; ++ct){
    floatx4 acc = {0.f,0.f,0.f,0.f};
    const short8* wrow = (const short8*)(lw + (16 * ct + r16) * 136);
    #pragma unroll
    for (int kk = 0; kk < 4; ++kk)
      acc = __builtin_amdgcn_mfma_f32_16x16x32_bf16(wrow[4 * kk + quad], xfrag[kk], acc, 0, 0, 0);
    int ch0 = ct * 16 + quad * 4;
    if (m < nrows){
      uint2 pk; pk.x = pack2(acc[0] * dv, acc[1] * dv);
      pk.y = pack2(acc[2] * dv, acc[3] * dv);
      ((uint2*)Gout)[((size_t)m * HH + ch0) >> 2] = pk;
    }
  }
}

// ---------------- aggregation: wave-per-node, 4 edges/step via 16-lane x 16B gathers ----------------
__global__ __launch_bounds__(256) void aggregate_k(const unsigned short* __restrict__ Gin,
                                                   const unsigned* __restrict__ ebuf,
                                                   const int* __restrict__ cnt,
                                                   const float* __restrict__ dinv,
                                                   const float* __restrict__ bias,
                                                   unsigned short* __restrict__ Xout){
  __shared__ float part[4][4][16][8];          // [wave][group][lane16][8ch] = 8 KB
  int wv = threadIdx.x >> 6, lane = threadIdx.x & 63;
  int node = blockIdx.x * 4 + wv;              // NN = 4*12500 exactly
  int g = lane >> 4, l = lane & 15;
  int c = min(cnt[node], CAP);
  unsigned rec = 0;                            // src=0, w=+0.0 bf16
  if (lane < c) rec = ebuf[(size_t)node * CAP + lane];
  float acc[8] = {0,0,0,0,0,0,0,0};
  const uint4* G4 = (const uint4*)Gin;
  int steps = (c + 3) >> 2;
  #pragma unroll 4
  for (int j = 0; j < steps; ++j){
    int idx = 4 * j + g;
    unsigned r = (unsigned)__shfl((int)rec, idx);
    int sx = r & 0xFFFF;
    float w = bfhi(r);
    if (idx >= c){ sx = 0; w = 0.0f; }
    uint4 q = G4[(size_t)sx * 16 + l];
    acc[0] = fmaf(w, bflo(q.x), acc[0]);
    acc[1] = fmaf(w, bfhi(q.x), acc[1]);
    acc[2] = fmaf(w, bflo(q.y), acc[2]);
    acc[3] = fmaf(w, bfhi(q.y), acc[3]);
    acc[4] = fmaf(w, bflo(q.z), acc[4]);
    acc[5] = fmaf(w, bfhi(q.z), acc[5]);
    acc[6] = fmaf(w, bflo(q.w), acc[6]);
    acc[7] = fmaf(w, bfhi(q.w), acc[7]);
  }
  #pragma unroll
  for (int k = 0; k < 8; ++k) part[wv][g][l][k] = acc[k];
  __syncthreads();
  int l0 = lane >> 2, k0 = (lane & 3) * 2;
  float a0 = part[wv][0][l0][k0]   + part[wv][1][l0][k0]   + part[wv][2][l0][k0]   + part[wv][3][l0][k0];
  float a1 = part[wv][0][l0][k0+1] + part[wv][1][l0][k0+1] + part[wv][2][l0][k0+1] + part[wv][3][l0][k0+1];
  unsigned gs = ((const unsigned*)Gin)[(size_t)node * 64 + lane];
  a0 += bflo(gs); a1 += bfhi(gs);
  float di = dinv[node];
  float2 bb = ((const float2*)bias)[lane];
  a0 = fmaxf(fmaf(di, a0, bb.x), 0.0f);
  a1 = fmaxf(fmaf(di, a1, bb.y), 0.0f);
  ((unsigned*)Xout)[(size_t)node * 64 + lane] = pack2(a0, a1);
}

// ---------------- pooling + BN stats: one block per graph (batch sorted) ----------------
__global__ __launch_bounds__(256) void pool_k(const unsigned short* __restrict__ H3,
                                              const int* __restrict__ gstart,
                                              float* __restrict__ S, float* bnsum, float* bnsqs,
                                              float* cntf){
  __shared__ float rs0[256], rs1[256], rq0[256], rq1[256];
  int b = blockIdx.x;
  int t = threadIdx.x, colc = t & 63, sub = t >> 6;
  int start = gstart[b], end = gstart[b + 1];
  const unsigned* Hrow = (const unsigned*)H3;
  float s0 = 0, s1 = 0, q0 = 0, q1 = 0;
  #pragma unroll 4
  for (int n = start + sub; n < end; n += 4){
    unsigned h = Hrow[(size_t)n * 64 + colc];
    float a = bflo(h), c = bfhi(h);
    s0 += a; s1 += c; q0 += a * a; q1 += c * c;
  }
  rs0[t] = s0; rs1[t] = s1; rq0[t] = q0; rq1[t] = q1;
  __syncthreads();
  if (sub == 0){
    float t0 = rs0[colc] + rs0[colc + 64] + rs0[colc + 128] + rs0[colc + 192];
    float t1 = rs1[colc] + rs1[colc + 64] + rs1[colc + 128] + rs1[colc + 192];
    float u0 = rq0[colc] + rq0[colc + 64] + rq0[colc + 128] + rq0[colc + 192];
    float u1 = rq1[colc] + rq1[colc + 64] + rq1[colc + 128] + rq1[colc + 192];
    S[b * HH + 2 * colc]     = t0;
    S[b * HH + 2 * colc + 1] = t1;
    atomicAdd(&bnsum[2 * colc], t0);
    atomicAdd(&bnsum[2 * colc + 1], t1);
    atomicAdd(&bnsqs[2 * colc], u0);
    atomicAdd(&bnsqs[2 * colc + 1], u1);
    if (t == 0) cntf[b] = (float)(end - start);
  }
}

// ---------------- BN affine on pooled means + MLP head (f32 out) ----------------
__global__ __launch_bounds__(64) void mlp_head_k(const float* __restrict__ S, const float* __restrict__ cntf,
                                                 const float* __restrict__ bnsum, const float* __restrict__ bnsqs,
                                                 const float* gamma, const float* beta,
                                                 const float* Wm1, const float* bm1,
                                                 const float* Wm2, const float* bm2,
                                                 float* out){
  __shared__ float gb[HH];
  __shared__ float t[MLPH];
  int b = blockIdx.x, j = threadIdx.x;
  float inv = 1.0f / fmaxf(cntf[b], 1.0f);
  for (int c = j; c < HH; c += 64){
    float mu = bnsum[c] * (1.0f / NN);
    float var = bnsqs[c] * (1.0f / NN) - mu * mu;
    float istd = rsqrtf(var + 1e-5f);
    float g = S[b * HH + c] * inv;
    gb[c] = (g - mu) * istd * gamma[c] + beta[c];
  }
  __syncthreads();
  float acc = bm1[j];
  for (int k = 0; k < HH; ++k) acc = fmaf(gb[k], Wm1[k * MLPH + j], acc);
  t[j] = acc;
  __syncthreads();
  if (j < CLS){
    float o = bm2[j];
    for (int k = 0; k < MLPH; ++k) o = fmaf(t[k], Wm2[k * CLS + j], o);
    out[b * CLS + j] = o;
  }
}

static inline size_t al(size_t x){ return (x + 255) & ~(size_t)255; }

extern "C" void kernel_launch(void* const* d_in, const int* in_sizes, int n_in,
                              void* d_out, int out_size, void* d_ws, size_t ws_size,
                              hipStream_t stream){
  const float* x     = (const float*)d_in[0];
  const int*   ei    = (const int*)d_in[1];          // [2][E]: src, dst
  const float* ea    = (const float*)d_in[2];
  const int*   batch = (const int*)d_in[3];
  const float* W1 = (const float*)d_in[4];
  const float* b1 = (const float*)d_in[5];
  const float* W2 = (const float*)d_in[6];
  const float* b2 = (const float*)d_in[7];
  const float* W3 = (const float*)d_in[8];
  const float* b3 = (const float*)d_in[9];
  const float* gamma = (const float*)d_in[10];
  const float* beta  = (const float*)d_in[11];
  const float* Wm1 = (const float*)d_in[12];
  const float* bm1 = (const float*)d_in[13];
  const float* Wm2 = (const float*)d_in[14];
  const float* bm2 = (const float*)d_in[15];
  const int* srcv = ei;
  const int* dstv = ei + EE;

  char* p = (char*)d_ws;
  float* dinv   = (float*)p;            p += al(NN * 4);
  int*   cnt    = (int*)p;              p += al(NN * 4);
  int*   cnts   = (int*)p;              p += al((size_t)SCAN_N * 4);
  int*   bsum   = (int*)p;              p += al(SCAN_BLKS * 4);
  int*   gstart = (int*)p;              p += al((BB + 1) * 4);
  int2*  ebin   = (int2*)p;             p += al((size_t)EE * 8);
  unsigned* ebuf = (unsigned*)p;        p += al((size_t)NN * CAP * 4);
  unsigned short* Wt1  = (unsigned short*)p; p += al(HH * HH * 2);
  unsigned short* Wt2  = (unsigned short*)p; p += al(HH * HH * 2);
  unsigned short* Wt3  = (unsigned short*)p; p += al(HH * HH * 2);
  unsigned short* bufA = (unsigned short*)p; p += al((size_t)NN * HH * 2);
  unsigned short* bufB = (unsigned short*)p; p += al((size_t)NN * HH * 2);
  float* S     = (float*)p;             p += al(BB * HH * 4);
  float* bnsum = (float*)p;             p += al(HH * 4);
  float* bnsqs = (float*)p;             p += al(HH * 4);
  float* cntf  = (float*)p;             p += al(BB * 4);

  const int nT = 256;
  dim3 gW((NN + 3) / 4);

  bin_count_k<<<dim3(NBLK), nT, 0, stream>>>(dstv, cnts);
  scanA_k<<<dim3(SCAN_BLKS), nT, 0, stream>>>(cnts, bsum);
  scanB_k<<<dim3(1), nT, 0, stream>>>(bsum);
  bin_scatter_k<<<dim3(NBLK), nT, 0, stream>>>(srcv, dstv, ea, cnts, bsum, ebin);
  bucket_sort_k<<<dim3(NBUK), nT, 0, stream>>>(ebin, cnts, bsum, ebuf, cnt, dinv);
  prep_k<<<dim3(193), nT, 0, stream>>>(W1, W2, W3, Wt1, Wt2, Wt3, batch, gstart, bnsum, bnsqs);

  dim3 gGemm((NN + 63) / 64);
  // layer 1 (f32 x read directly):  x -> bufA(G1) -> bufB(X2)
  gemm64_f32_k<<<gGemm, nT, 0, stream>>>(x, Wt1, dinv, bufA, NN);
  aggregate_k<<<gW, nT, 0, stream>>>(bufA, ebuf, cnt, dinv, b1, bufB);
  // layer 2
  gemm64_k<<<gGemm, nT, 0, stream>>>(bufB, Wt2, dinv, bufA, NN);
  aggregate_k<<<gW, nT, 0, stream>>>(bufA, ebuf, cnt, dinv, b2, bufB);
  // layer 3
  gemm64_k<<<gGemm, nT, 0, stream>>>(bufB, Wt3, dinv, bufA, NN);
  aggregate_k<<<gW, nT, 0, stream>>>(bufA, ebuf, cnt, dinv, b3, bufB);

  pool_k<<<dim3(BB), nT, 0, stream>>>(bufB, gstart, S, bnsum, bnsqs, cntf);
  mlp_head_k<<<dim3(BB), dim3(64), 0, stream>>>(S, cntf, bnsum, bnsqs, gamma, beta,
                                                Wm1, bm1, Wm2, bm2, (float*)d_out);
}